// Round 9
// baseline (286.597 us; speedup 1.0000x reference)
//
#include <hip/hip_runtime.h>
#include <math.h>

typedef unsigned long long u64;
typedef unsigned int u32;

#define NB 16
#define SL 1024
#define DIM 16
#define MDIM 16
#define KNN 8
#define CH 64    /* coors hidden */
#define NHID 32  /* node hidden */
#define LN_EPS 1e-5f
#define PST 144  /* P row stride: 4 chunks of 36 (33 units + 3 zero pad) */

// silu via hw exp + hw rcp: 5 VALU vs ~12 for div-based (no -ffast-math here)
__device__ __forceinline__ float silu_f(float x) {
    const float e = __expf(-x);
    return x * __builtin_amdgcn_rcpf(1.0f + e);
}

// ---------------- init: feats/coords copy + fused phi for layer 0 ----------------
__global__ __launch_bounds__(256) void init_kernel(
    const float* __restrict__ coords, const int* __restrict__ residues,
    const float* __restrict__ token_emb, const float* __restrict__ pos_emb,
    const float* __restrict__ w1tp, const float* __restrict__ g_eb1,
    float* __restrict__ coordsA, float* __restrict__ featsA,
    float* __restrict__ Pout)
{
    const int t = blockIdx.x * 256 + threadIdx.x;
    const int node = t >> 2;
    const int part = t & 3;
    const int l = node & (SL - 1);
    const int r = residues[node];
    float f[16];
    {
        const float4* te = (const float4*)(token_emb + (size_t)r * DIM);
        const float4* pe = (const float4*)(pos_emb + (size_t)l * DIM);
#pragma unroll
        for (int q = 0; q < 4; ++q) {
            float4 a = te[q], b4 = pe[q];
            f[4*q+0] = a.x + b4.x; f[4*q+1] = a.y + b4.y;
            f[4*q+2] = a.z + b4.z; f[4*q+3] = a.w + b4.w;
        }
    }
    if (part == 0) {
        float4* fo = (float4*)(featsA + (size_t)node * DIM);
#pragma unroll
        for (int q = 0; q < 4; ++q)
            fo[q] = make_float4(f[4*q], f[4*q+1], f[4*q+2], f[4*q+3]);
        coordsA[node * 3 + 0] = coords[node * 3 + 0];
        coordsA[node * 3 + 1] = coords[node * 3 + 1];
        coordsA[node * 3 + 2] = coords[node * 3 + 2];
    }
    const int ubase = (part & 1) * 33;
    const int wbase = (part < 2) ? 0 : 66;
    float res[36];
    res[33] = 0.f; res[34] = 0.f; res[35] = 0.f;
#pragma unroll
    for (int oo = 0; oo < 33; ++oo) {     // FULL unroll: res[] stays in registers
        const int u = ubase + oo;
        const float* wr = w1tp + (wbase + u) * 16;
        float a0 = (part < 2) ? g_eb1[u] : 0.0f;
        float a1 = 0.f, a2 = 0.f, a3 = 0.f;
#pragma unroll
        for (int c = 0; c < 16; c += 4) {
            a0 = fmaf(f[c + 0], wr[c + 0], a0);
            a1 = fmaf(f[c + 1], wr[c + 1], a1);
            a2 = fmaf(f[c + 2], wr[c + 2], a2);
            a3 = fmaf(f[c + 3], wr[c + 3], a3);
        }
        res[oo] = (a0 + a1) + (a2 + a3);
    }
    float4* op = (float4*)(Pout + (size_t)node * PST + part * 36);
#pragma unroll
    for (int q = 0; q < 9; ++q)
        op[q] = make_float4(res[4*q], res[4*q+1], res[4*q+2], res[4*q+3]);
}

// ---------------- weight transpose/pack ----------------
__global__ __launch_bounds__(256) void pack_kernel(
    const float* __restrict__ ew1, const float* __restrict__ ew2,
    const float* __restrict__ cw1,
    const float* __restrict__ nw1, const float* __restrict__ nw2,
    float* __restrict__ w1tp, float* __restrict__ w1rp, float* __restrict__ w2p,
    float* __restrict__ cw1t, float* __restrict__ nw1t, float* __restrict__ nw2t)
{
    const int stride = gridDim.x * 256;
    const int t0 = blockIdx.x * 256 + threadIdx.x;
    for (int idx = t0; idx < 3 * 132 * 16; idx += stride) {
        int d = idx / (132 * 16); int r = idx - d * 132 * 16; int o = r >> 4; int c = r & 15;
        int u = (o < 66) ? o : (o - 66);
        int cc = (o < 66) ? c : (16 + c);
        w1tp[idx] = ew1[(d * 33 + cc) * 66 + u];
    }
    for (int idx = t0; idx < 3 * 72; idx += stride) {
        int d = idx / 72; int o = idx - d * 72; int hh = o / 36; int uu = o - hh * 36;
        w1rp[idx] = (uu < 33) ? ew1[(d * 33 + 32) * 66 + hh * 33 + uu] : 0.0f;
    }
    for (int idx = t0; idx < 3 * 72 * 16; idx += stride) {
        int d = idx / (72 * 16); int r = idx - d * 72 * 16; int u = r >> 4; int v = r & 15;
        int hh = u / 36; int uu = u - hh * 36;
        w2p[idx] = (uu < 33) ? ew2[(d * 66 + hh * 33 + uu) * 16 + v] : 0.0f;
    }
    for (int idx = t0; idx < 3 * CH * 16; idx += stride) {
        int d = idx / (CH * 16); int r = idx - d * CH * 16; int t = r >> 4; int v = r & 15;
        cw1t[(d * CH + t) * 16 + v] = cw1[(d * 16 + v) * CH + t];
    }
    for (int idx = t0; idx < 3 * NHID * 32; idx += stride) {
        int d = idx / (NHID * 32); int r = idx - d * NHID * 32; int u = r >> 5; int c = r & 31;
        nw1t[(d * NHID + u) * 32 + c] = nw1[(d * 32 + c) * NHID + u];
    }
    for (int idx = t0; idx < 3 * 16 * 32; idx += stride) {
        int d = idx / (16 * 32); int r = idx - d * 16 * 32; int c = r >> 5; int u = r & 31;
        nw2t[(d * 16 + c) * 32 + u] = nw2[(d * 32 + u) * 16 + c];
    }
}

// ---------------- kNN: masked form (1e5 sentinel is load-bearing!) ----------------
__device__ __forceinline__ void merge8(u32* a, const u32* bb) {
    u32 c[8];
#pragma unroll
    for (int t = 0; t < 8; ++t) c[t] = min(a[t], bb[7 - t]);
#define MCAS(x, y) { u32 mn = min(c[x], c[y]); u32 mx = max(c[x], c[y]); c[x] = mn; c[y] = mx; }
    MCAS(0, 4) MCAS(1, 5) MCAS(2, 6) MCAS(3, 7)
    MCAS(0, 2) MCAS(1, 3) MCAS(4, 6) MCAS(5, 7)
    MCAS(0, 1) MCAS(2, 3) MCAS(4, 5) MCAS(6, 7)
#undef MCAS
#pragma unroll
    for (int t = 0; t < 8; ++t) a[t] = c[t];
}

__global__ __launch_bounds__(1024) void knn_kernel(
    const float* __restrict__ coords, const int* __restrict__ lengths,
    int* __restrict__ idxbuf)
{
    __shared__ __align__(16) float4 s_cand[SL];   // 16 KB (padded xyz)
    __shared__ u32 lists[16][64][9];              // 36 KB, pad 9 vs bank conflicts
    const int tid = threadIdx.x;
    const int b = blockIdx.x >> 4;
    const int i0 = (blockIdx.x & 15) << 6;
    const int len = lengths[b];
    const float* cb = coords + (size_t)b * SL * 3;
    for (int idx = tid; idx < SL; idx += 1024) {
        const float* cp = cb + idx * 3;
        s_cand[idx] = make_float4(cp[0], cp[1], cp[2], 0.0f);
    }
    __syncthreads();

    const int wv = tid >> 6;     // candidate slice 0..15
    const int lane = tid & 63;   // query within group
    const int i = i0 + lane;
    const bool mi = i < len;
    const float4 qi = s_cand[i];
    const float xi = qi.x, yi = qi.y, zi = qi.z;

    u32 lst[8];
#pragma unroll
    for (int t = 0; t < 8; ++t) lst[t] = 0xFFFFFFFFu;

    const int jbase = wv << 6;
#pragma unroll 4
    for (int jj = 0; jj < 64; ++jj) {
        const int j = jbase + jj;
        const float4 cj = s_cand[j];   // wave-uniform addr -> LDS broadcast
        const float dx = xi - cj.x, dy = yi - cj.y, dz = zi - cj.z;
        const float dist = dx * dx + dy * dy + dz * dz;
        const int dij = j - i;
        const bool pm = mi && (j < len);
        const bool adjx = (dij == 1) | (dij == -1);
        float v = pm ? (adjx ? 0.0f : dist) : 1e5f;
        v = (dij == 0) ? -1.0f : v;
        u32 bits = __float_as_uint(v);
        bits ^= (u32)((int)bits >> 31) | 0x80000000u;
        const u32 key = (bits & 0xFFFFFC00u) | (u32)j;
        // sorted-insert: lst[p] = min(max(key, lst[p-1]), lst[p]) -- 2 VALU/level
#pragma unroll
        for (int p = 7; p >= 1; --p)
            lst[p] = min(max(key, lst[p - 1]), lst[p]);
        lst[0] = min(key, lst[0]);
    }

#pragma unroll
    for (int t = 0; t < 8; ++t) lists[wv][lane][t] = lst[t];
    __syncthreads();

    if (tid < 512) {
        const int p = tid >> 6, q = tid & 63;
        u32 a[8], bb[8];
#pragma unroll
        for (int t = 0; t < 8; ++t) { a[t] = lists[2 * p][q][t]; bb[t] = lists[2 * p + 1][q][t]; }
        merge8(a, bb);
#pragma unroll
        for (int t = 0; t < 8; ++t) lists[2 * p][q][t] = a[t];
    }
    __syncthreads();
    if (tid < 256) {
        const int p = tid >> 6, q = tid & 63;
        u32 a[8], bb[8];
#pragma unroll
        for (int t = 0; t < 8; ++t) { a[t] = lists[4 * p][q][t]; bb[t] = lists[4 * p + 2][q][t]; }
        merge8(a, bb);
#pragma unroll
        for (int t = 0; t < 8; ++t) lists[4 * p][q][t] = a[t];
    }
    __syncthreads();
    if (tid < 128) {
        const int p = tid >> 6, q = tid & 63;
        u32 a[8], bb[8];
#pragma unroll
        for (int t = 0; t < 8; ++t) { a[t] = lists[8 * p][q][t]; bb[t] = lists[8 * p + 4][q][t]; }
        merge8(a, bb);
#pragma unroll
        for (int t = 0; t < 8; ++t) lists[8 * p][q][t] = a[t];
    }
    __syncthreads();
    if (tid < 64) {
        const int q = tid;
        u32 a[8], bb[8];
#pragma unroll
        for (int t = 0; t < 8; ++t) { a[t] = lists[0][q][t]; bb[t] = lists[8][q][t]; }
        merge8(a, bb);
        const size_t node = (size_t)b * SL + i0 + q;
        int4 r0 = make_int4((int)(a[0] & 1023u), (int)(a[1] & 1023u), (int)(a[2] & 1023u), (int)(a[3] & 1023u));
        int4 r1 = make_int4((int)(a[4] & 1023u), (int)(a[5] & 1023u), (int)(a[6] & 1023u), (int)(a[7] & 1023u));
        ((int4*)idxbuf)[node * 2 + 0] = r0;
        ((int4*)idxbuf)[node * 2 + 1] = r1;
    }
}

// ---------------- EGNN layer: TWO NODES PER THREAD ----------------
// Diagnosis (r0-r8): kernel is LDS-pipe-issue-bound -- broadcast weight ds_reads
// (~280 b128/wave) + ~122 bpermutes dominate (~30us of the 45us). Fix: each thread
// runs its lane-role for nodes nA and nA+16, sharing every weight read (CSE'd) so
// per-CU weight-read issue halves. Grid 1024->512 blocks.
// lane = g(2) | h(1) | k(3): 16 lanes per node-slot, 2 nodes per slot.
__global__ __launch_bounds__(256, 4) void layer_kernel(
    const int d,
    const float* __restrict__ coordsIn, float* __restrict__ coordsOut,
    const float* __restrict__ featsIn, float* __restrict__ featsOut,
    const float* __restrict__ Pbuf,
    const int* __restrict__ idxbuf, const int* __restrict__ lengths,
    const float* __restrict__ w1rp, const float* __restrict__ w2p,
    const float* __restrict__ g_eb2,
    const float* __restrict__ cw1t, const float* __restrict__ g_cb1,
    const float* __restrict__ g_cw2, const float* __restrict__ g_cb2,
    const float* __restrict__ g_lng, const float* __restrict__ g_lnb,
    const float* __restrict__ nw1t, const float* __restrict__ g_nb1,
    const float* __restrict__ nw2t, const float* __restrict__ g_nb2,
    const float* __restrict__ w1tp_all, const float* __restrict__ g_eb1,
    float* __restrict__ PbufOut)
{
    __shared__ float s_w2e[72 * 16];                 // 4608 B
    __shared__ __align__(16) float s_w1r[72];
    __shared__ float s_cw1[CH * 16];                 // 4096 B
    __shared__ float s_cw2v[CH];
    __shared__ float s_nw1[NHID * 36];               // padded rows: bank spread
    __shared__ float s_nw2[16 * 36];
    __shared__ float s_eb2[16], s_cb1[CH];
    __shared__ float s_lng[16], s_lnb[16], s_nb1[32], s_nb2[16];
    __shared__ float s_cb2v;

    const int tid = threadIdx.x;
    for (int t = tid; t < 72 * 16; t += 256) s_w2e[t] = w2p[d * 72 * 16 + t];
    for (int t = tid; t < CH * 16; t += 256) s_cw1[t] = cw1t[d * CH * 16 + t];
    for (int t = tid; t < NHID * 32; t += 256) s_nw1[(t >> 5) * 36 + (t & 31)] = nw1t[d * NHID * 32 + t];
    for (int t = tid; t < 16 * 32; t += 256) s_nw2[(t >> 5) * 36 + (t & 31)] = nw2t[d * 16 * 32 + t];
    if (tid < 72) s_w1r[tid] = w1rp[d * 72 + tid];
    if (tid < CH) { s_cw2v[tid] = g_cw2[d * CH + tid]; s_cb1[tid] = g_cb1[d * CH + tid]; }
    if (tid < 16) {
        s_eb2[tid] = g_eb2[d * 16 + tid];
        s_lng[tid] = g_lng[d * 16 + tid];
        s_lnb[tid] = g_lnb[d * 16 + tid];
        s_nb2[tid] = g_nb2[d * 16 + tid];
    }
    if (tid < 32) s_nb1[tid] = g_nb1[d * 32 + tid];
    if (tid == 0) s_cb2v = g_cb2[d];

    const int lane = tid & 63;
    const int h = (lane >> 3) & 1;               // lane-bit half
    const int k = lane & 7;                      // edge within node
    const int sub = lane & 15;
    const int nA = blockIdx.x * 32 + (tid >> 4); // node A
    const int nB = nA + 16;                      // node B (same batch: 1024%32==0)
    const int b = nA >> 10;
    const int len = lengths[b];
    const int jA = idxbuf[nA * 8 + k];
    const int jB = idxbuf[nB * 8 + k];
    const bool emA = ((nA & 1023) < len) && (jA < len);
    const bool emB = ((nB & 1023) < len) && (jB < len);

    // ---- coords ----
    float ciA[3], relA[3], ciB[3], relB[3];
    {
        const float* cpA = coordsIn + (size_t)nA * 3;
        const float* cqA = coordsIn + ((size_t)b * SL + jA) * 3;
        ciA[0] = cpA[0]; ciA[1] = cpA[1]; ciA[2] = cpA[2];
        relA[0] = ciA[0] - cqA[0]; relA[1] = ciA[1] - cqA[1]; relA[2] = ciA[2] - cqA[2];
        const float* cpB = coordsIn + (size_t)nB * 3;
        const float* cqB = coordsIn + ((size_t)b * SL + jB) * 3;
        ciB[0] = cpB[0]; ciB[1] = cpB[1]; ciB[2] = cpB[2];
        relB[0] = ciB[0] - cqB[0]; relB[1] = ciB[1] - cqB[1]; relB[2] = ciB[2] - cqB[2];
    }
    const float rdA = fmaf(relA[0], relA[0], fmaf(relA[1], relA[1], relA[2] * relA[2]));
    const float rdB = fmaf(relB[0], relB[0], fmaf(relB[1], relB[1], relB[2] * relB[2]));

    const int ub = h * 36;
    const float* PiA = Pbuf + (size_t)nA * PST + ub;
    const float* PjA = Pbuf + ((size_t)b * SL + jA) * PST + 72 + ub;
    const float* PiB = Pbuf + (size_t)nB * PST + ub;
    const float* PjB = Pbuf + ((size_t)b * SL + jB) * PST + 72 + ub;

    __syncthreads();   // weights staged (only barrier in this kernel)

    // ---- edge MLP: layer-1 partials + layer-2 accumulate, weights shared A/B ----
    float maccA[16], maccB[16];
#pragma unroll
    for (int v = 0; v < 16; ++v) {
        const float e0 = h ? 0.0f : s_eb2[v];
        maccA[v] = e0; maccB[v] = e0;
    }
#pragma unroll
    for (int c4 = 0; c4 < 9; ++c4) {
        const float4 paA = *(const float4*)(PiA + 4 * c4);
        const float4 pbA = *(const float4*)(PjA + 4 * c4);
        const float4 paB = *(const float4*)(PiB + 4 * c4);
        const float4 pbB = *(const float4*)(PjB + 4 * c4);
        const int u0 = ub + c4 * 4;
        const float4 w1r4 = *(const float4*)&s_w1r[u0];
        const float huA0 = silu_f(fmaf(rdA, w1r4.x, paA.x + pbA.x));
        const float huA1 = silu_f(fmaf(rdA, w1r4.y, paA.y + pbA.y));
        const float huA2 = silu_f(fmaf(rdA, w1r4.z, paA.z + pbA.z));
        const float huA3 = silu_f(fmaf(rdA, w1r4.w, paA.w + pbA.w));
        const float huB0 = silu_f(fmaf(rdB, w1r4.x, paB.x + pbB.x));
        const float huB1 = silu_f(fmaf(rdB, w1r4.y, paB.y + pbB.y));
        const float huB2 = silu_f(fmaf(rdB, w1r4.z, paB.z + pbB.z));
        const float huB3 = silu_f(fmaf(rdB, w1r4.w, paB.w + pbB.w));
        const float* w2r = &s_w2e[u0 * 16];
#pragma unroll
        for (int v = 0; v < 16; ++v) {
            const float w0 = w2r[v], w1 = w2r[16 + v], w2_ = w2r[32 + v], w3 = w2r[48 + v];
            maccA[v] = fmaf(huA3, w3, fmaf(huA2, w2_, fmaf(huA1, w1, fmaf(huA0, w0, maccA[v]))));
            maccB[v] = fmaf(huB3, w3, fmaf(huB2, w2_, fmaf(huB1, w1, fmaf(huB0, w0, maccB[v]))));
        }
    }

    // ---- combine halves in-wave (partner = lane^8) ----
    float mmA[16], mmB[16];
#pragma unroll
    for (int v = 0; v < 16; ++v) {
        mmA[v] = silu_f(maccA[v] + __shfl_xor(maccA[v], 8, 64));
        mmB[v] = silu_f(maccB[v] + __shfl_xor(maccB[v], 8, 64));
    }

    // ---- coors MLP, t-range [h*32, h*32+32), weights shared A/B ----
    const int tb = h * 32;
    float waA = 0.f, waB = 0.f;
#pragma unroll 4
    for (int tt = 0; tt < 32; ++tt) {
        const float* cr = &s_cw1[(tb + tt) * 16];
        const float bias = s_cb1[tb + tt];
        float a0A = bias, a1A = 0.f, a0B = bias, a1B = 0.f;
#pragma unroll
        for (int v = 0; v < 16; v += 2) {
            a0A = fmaf(mmA[v], cr[v], a0A);
            a1A = fmaf(mmA[v + 1], cr[v + 1], a1A);
            a0B = fmaf(mmB[v], cr[v], a0B);
            a1B = fmaf(mmB[v + 1], cr[v + 1], a1B);
        }
        const float cw2v = s_cw2v[tb + tt];
        waA = fmaf(silu_f(a0A + a1A), cw2v, waA);
        waB = fmaf(silu_f(a0B + a1B), cw2v, waB);
    }
    const float waoA = __shfl_xor(waA, 8, 64);
    const float waoB = __shfl_xor(waB, 8, 64);
    const float weA = emA ? (waA + waoA + s_cb2v) : 0.f;
    const float weB = emB ? (waB + waoB + s_cb2v) : 0.f;

    // ---- coordinate update: reduce over 8 edges (xor over k bits) ----
    float wr0A = weA * relA[0], wr1A = weA * relA[1], wr2A = weA * relA[2];
    float wr0B = weB * relB[0], wr1B = weB * relB[1], wr2B = weB * relB[2];
#pragma unroll
    for (int s = 1; s < 8; s <<= 1) {
        wr0A += __shfl_xor(wr0A, s, 64);
        wr1A += __shfl_xor(wr1A, s, 64);
        wr2A += __shfl_xor(wr2A, s, 64);
        wr0B += __shfl_xor(wr0B, s, 64);
        wr1B += __shfl_xor(wr1B, s, 64);
        wr2B += __shfl_xor(wr2B, s, 64);
    }
    if ((lane & 15) == 0) {
        coordsOut[(size_t)nA * 3 + 0] = ciA[0] + wr0A;
        coordsOut[(size_t)nA * 3 + 1] = ciA[1] + wr1A;
        coordsOut[(size_t)nA * 3 + 2] = ciA[2] + wr2A;
        coordsOut[(size_t)nB * 3 + 0] = ciB[0] + wr0B;
        coordsOut[(size_t)nB * 3 + 1] = ciB[1] + wr1B;
        coordsOut[(size_t)nB * 3 + 2] = ciB[2] + wr2B;
    }

    // ---- feats loads (issued early to hide under m_i shuffle storm) ----
    float fiA[16], fiB[16];
    {
        const float4* ppA = (const float4*)(featsIn + (size_t)nA * DIM);
        float4 a0 = ppA[0], a1 = ppA[1], a2 = ppA[2], a3 = ppA[3];
        fiA[0]=a0.x; fiA[1]=a0.y; fiA[2]=a0.z; fiA[3]=a0.w;
        fiA[4]=a1.x; fiA[5]=a1.y; fiA[6]=a1.z; fiA[7]=a1.w;
        fiA[8]=a2.x; fiA[9]=a2.y; fiA[10]=a2.z; fiA[11]=a2.w;
        fiA[12]=a3.x; fiA[13]=a3.y; fiA[14]=a3.z; fiA[15]=a3.w;
        const float4* ppB = (const float4*)(featsIn + (size_t)nB * DIM);
        float4 b0 = ppB[0], b1 = ppB[1], b2 = ppB[2], b3 = ppB[3];
        fiB[0]=b0.x; fiB[1]=b0.y; fiB[2]=b0.z; fiB[3]=b0.w;
        fiB[4]=b1.x; fiB[5]=b1.y; fiB[6]=b1.z; fiB[7]=b1.w;
        fiB[8]=b2.x; fiB[9]=b2.y; fiB[10]=b2.z; fiB[11]=b2.w;
        fiB[12]=b3.x; fiB[13]=b3.y; fiB[14]=b3.z; fiB[15]=b3.w;
    }
    const float fiSubA = featsIn[(size_t)nA * DIM + sub];   // residual channel (no runtime reg-index)
    const float fiSubB = featsIn[(size_t)nB * DIM + sub];

    // ---- m_i ----
    float miA[16], miB[16];
#pragma unroll
    for (int v = 0; v < 16; ++v) {
        miA[v] = emA ? mmA[v] : 0.f;
        miB[v] = emB ? mmB[v] : 0.f;
    }
#pragma unroll
    for (int s = 1; s < 8; s <<= 1) {
#pragma unroll
        for (int v = 0; v < 16; ++v) {
            miA[v] += __shfl_xor(miA[v], s, 64);
            miB[v] += __shfl_xor(miB[v], s, 64);
        }
    }

    // ---- LayerNorm (pure VALU) ----
    float nnA[16], nnB[16];
    {
        float mu = 0.f;
#pragma unroll
        for (int c = 0; c < 16; ++c) mu += fiA[c];
        mu *= 0.0625f;
        float var = 0.f;
#pragma unroll
        for (int c = 0; c < 16; ++c) { const float dd = fiA[c] - mu; var = fmaf(dd, dd, var); }
        var *= 0.0625f;
        const float rs = rsqrtf(var + LN_EPS);
#pragma unroll
        for (int c = 0; c < 16; ++c) nnA[c] = fmaf((fiA[c] - mu) * rs, s_lng[c], s_lnb[c]);
    }
    {
        float mu = 0.f;
#pragma unroll
        for (int c = 0; c < 16; ++c) mu += fiB[c];
        mu *= 0.0625f;
        float var = 0.f;
#pragma unroll
        for (int c = 0; c < 16; ++c) { const float dd = fiB[c] - mu; var = fmaf(dd, dd, var); }
        var *= 0.0625f;
        const float rs = rsqrtf(var + LN_EPS);
#pragma unroll
        for (int c = 0; c < 16; ++c) nnB[c] = fmaf((fiB[c] - mu) * rs, s_lng[c], s_lnb[c]);
    }

    // ---- node MLP hidden: lane owns units sub*2, sub*2+1; weights shared A/B ----
    float nhA[2], nhB[2];
#pragma unroll
    for (int q = 0; q < 2; ++q) {
        const int u = sub * 2 + q;
        const float* nr = &s_nw1[u * 36];
        const float bias = s_nb1[u];
        float a0A = bias, a1A = 0.f, a0B = bias, a1B = 0.f;
#pragma unroll
        for (int c = 0; c < 16; c += 2) {
            a0A = fmaf(nnA[c], nr[c], a0A);
            a1A = fmaf(nnA[c + 1], nr[c + 1], a1A);
            a0B = fmaf(nnB[c], nr[c], a0B);
            a1B = fmaf(nnB[c + 1], nr[c + 1], a1B);
        }
#pragma unroll
        for (int v = 0; v < 16; v += 2) {
            a0A = fmaf(miA[v], nr[16 + v], a0A);
            a1A = fmaf(miA[v + 1], nr[16 + v + 1], a1A);
            a0B = fmaf(miB[v], nr[16 + v], a0B);
            a1B = fmaf(miB[v + 1], nr[16 + v + 1], a1B);
        }
        nhA[q] = silu_f(a0A + a1A);
        nhB[q] = silu_f(a0B + a1B);
    }

    // ---- node MLP out: lane computes channel sub; weights shared A/B ----
    const int nbase = lane & ~15;
    const float* w2c = &s_nw2[sub * 36];
    float oA = s_nb2[sub], oB = s_nb2[sub];
#pragma unroll
    for (int u = 0; u < 32; ++u) {
        const float w = w2c[u];
        oA = fmaf(__shfl(nhA[u & 1], nbase + (u >> 1), 64), w, oA);
        oB = fmaf(__shfl(nhB[u & 1], nbase + (u >> 1), 64), w, oB);
    }
    const float foA = fiSubA + oA;
    const float foB = fiSubB + oB;
    featsOut[(size_t)nA * DIM + sub] = foA;
    featsOut[(size_t)nB * DIM + sub] = foB;

    // ---- fused phi for layer d+1: weights (global, L1/L2) shared A/B ----
    if (d < 2) {
        float frA[16], frB[16];
#pragma unroll
        for (int c = 0; c < 16; ++c) {
            frA[c] = __shfl(foA, nbase + c, 64);
            frB[c] = __shfl(foB, nbase + c, 64);
        }
        const float* wbase = w1tp_all + (d + 1) * 132 * 16;
        const float* bbase = g_eb1 + (d + 1) * 66;
        float* PoutA = PbufOut + (size_t)nA * PST;
        float* PoutB = PbufOut + (size_t)nB * PST;
#pragma unroll
        for (int q = 0; q < 9; ++q) {
            const int col = sub + (q << 4);
            const int ch = (col >= 108) ? 3 : (col >= 72) ? 2 : (col >= 36) ? 1 : 0;
            const int uu = col - ch * 36;
            const bool valid = uu < 33;
            const int u = ((ch & 1) ? 33 : 0) + uu;
            const int uc = valid ? u : 0;
            const int widx = valid ? ((ch < 2) ? u : 66 + u) : 0;
            const float bias = (valid && ch < 2) ? bbase[uc] : 0.0f;
            float a0A = bias, a1A = 0.f, a2A = 0.f, a3A = 0.f;
            float a0B = bias, a1B = 0.f, a2B = 0.f, a3B = 0.f;
            const float* wr = wbase + widx * 16;
#pragma unroll
            for (int cc = 0; cc < 16; cc += 4) {
                const float w0 = wr[cc + 0], w1 = wr[cc + 1], w2_ = wr[cc + 2], w3 = wr[cc + 3];
                a0A = fmaf(frA[cc + 0], w0, a0A);
                a1A = fmaf(frA[cc + 1], w1, a1A);
                a2A = fmaf(frA[cc + 2], w2_, a2A);
                a3A = fmaf(frA[cc + 3], w3, a3A);
                a0B = fmaf(frB[cc + 0], w0, a0B);
                a1B = fmaf(frB[cc + 1], w1, a1B);
                a2B = fmaf(frB[cc + 2], w2_, a2B);
                a3B = fmaf(frB[cc + 3], w3, a3B);
            }
            PoutA[col] = valid ? ((a0A + a1A) + (a2A + a3A)) : 0.0f;
            PoutB[col] = valid ? ((a0B + a1B) + (a2B + a3B)) : 0.0f;
        }
    }
}

// ---------------- final projection ----------------
__global__ __launch_bounds__(256) void final_kernel(
    const float* __restrict__ feats, const float* __restrict__ fw,
    const float* __restrict__ fb, float* __restrict__ out)
{
    const int nid = blockIdx.x * 256 + threadIdx.x;
    if (nid >= NB * SL) return;
    float f[DIM];
#pragma unroll
    for (int c = 0; c < DIM; ++c) f[c] = feats[nid * DIM + c];
#pragma unroll
    for (int o = 0; o < 3; ++o) {
        float acc = fb[o];
#pragma unroll
        for (int c = 0; c < DIM; ++c) acc = fmaf(f[c], fw[c * 3 + o], acc);
        out[nid * 3 + o] = acc;
    }
}

extern "C" void kernel_launch(void* const* d_in, const int* in_sizes, int n_in,
                              void* d_out, int out_size, void* d_ws, size_t ws_size,
                              hipStream_t stream) {
    const float* coords    = (const float*)d_in[0];
    const int*   residues  = (const int*)d_in[1];
    const int*   lengths   = (const int*)d_in[2];
    const float* token_emb = (const float*)d_in[3];
    const float* pos_emb   = (const float*)d_in[4];
    const float* ew1 = (const float*)d_in[5];
    const float* eb1 = (const float*)d_in[6];
    const float* ew2 = (const float*)d_in[7];
    const float* eb2 = (const float*)d_in[8];
    const float* cw1 = (const float*)d_in[9];
    const float* cb1 = (const float*)d_in[10];
    const float* cw2 = (const float*)d_in[11];
    const float* cb2 = (const float*)d_in[12];
    const float* lng = (const float*)d_in[13];
    const float* lnb = (const float*)d_in[14];
    const float* nw1 = (const float*)d_in[15];
    const float* nb1 = (const float*)d_in[16];
    const float* nw2 = (const float*)d_in[17];
    const float* nb2 = (const float*)d_in[18];
    const float* fw  = (const float*)d_in[19];
    const float* fb  = (const float*)d_in[20];

    float* ws = (float*)d_ws;
    float* coordsA = ws;
    float* coordsB = coordsA + NB * SL * 3;
    float* featsA  = coordsB + NB * SL * 3;
    float* featsB  = featsA + NB * SL * DIM;
    int*   idxbuf  = (int*)(featsB + NB * SL * DIM);
    float* w1tp = (float*)(idxbuf + NB * SL * KNN);     // 3*132*16
    float* w1rp = w1tp + 3 * 132 * 16;                  // 3*72
    float* w2p  = w1rp + 3 * 72;                        // 3*72*16
    float* cw1t = w2p + 3 * 72 * 16;                    // 3*64*16
    float* nw1t = cw1t + 3 * CH * 16;                   // 3*32*32
    float* nw2t = nw1t + 3 * NHID * 32;                 // 3*16*32
    float* PbufA = nw2t + 3 * 16 * 32;                  // 16384*144
    float* PbufB = PbufA + (size_t)NB * SL * PST;       // 16384*144

    pack_kernel<<<32, 256, 0, stream>>>(ew1, ew2, cw1, nw1, nw2, w1tp, w1rp, w2p, cw1t, nw1t, nw2t);
    init_kernel<<<NB * SL * 4 / 256, 256, 0, stream>>>(coords, residues, token_emb, pos_emb,
                                                        w1tp, eb1, coordsA, featsA, PbufA);

    float* cIn = coordsA; float* cOut = coordsB;
    float* fIn = featsA;  float* fOut = featsB;
    float* pIn = PbufA;   float* pOut = PbufB;
    for (int d = 0; d < 3; ++d) {
        knn_kernel<<<NB * SL / 64, 1024, 0, stream>>>(cIn, lengths, idxbuf);
        layer_kernel<<<NB * SL * KNN / 256, 256, 0, stream>>>(d, cIn, cOut, fIn, fOut, pIn, idxbuf, lengths,
            w1rp, w2p, eb2, cw1t, cb1, cw2, cb2, lng, lnb, nw1t, nb1, nw2t, nb2,
            w1tp, eb1, pOut);
        float* t;
        t = cIn; cIn = cOut; cOut = t;
        t = fIn; fIn = fOut; fOut = t;
        t = pIn; pIn = pOut; pOut = t;
    }

    final_kernel<<<NB * SL / 256, 256, 0, stream>>>(fIn, fw, fb, (float*)d_out);
}

// Round 10
// 269.286 us; speedup vs baseline: 1.0643x; 1.0643x over previous
//
#include <hip/hip_runtime.h>
#include <math.h>

typedef unsigned long long u64;
typedef unsigned int u32;

#define NB 16
#define SL 1024
#define DIM 16
#define MDIM 16
#define KNN 8
#define CH 64    /* coors hidden */
#define NHID 32  /* node hidden */
#define LN_EPS 1e-5f
#define PST 144  /* P row stride: 4 chunks of 36 (33 units + 3 zero pad) */

// silu via hw exp + hw rcp: 5 VALU vs ~12 for div-based (no -ffast-math here)
__device__ __forceinline__ float silu_f(float x) {
    const float e = __expf(-x);
    return x * __builtin_amdgcn_rcpf(1.0f + e);
}

// ---------------- init: feats/coords copy + fused phi for layer 0 ----------------
__global__ __launch_bounds__(256) void init_kernel(
    const float* __restrict__ coords, const int* __restrict__ residues,
    const float* __restrict__ token_emb, const float* __restrict__ pos_emb,
    const float* __restrict__ w1tp, const float* __restrict__ g_eb1,
    float* __restrict__ coordsA, float* __restrict__ featsA,
    float* __restrict__ Pout)
{
    const int t = blockIdx.x * 256 + threadIdx.x;
    const int node = t >> 2;
    const int part = t & 3;
    const int l = node & (SL - 1);
    const int r = residues[node];
    float f[16];
    {
        const float4* te = (const float4*)(token_emb + (size_t)r * DIM);
        const float4* pe = (const float4*)(pos_emb + (size_t)l * DIM);
#pragma unroll
        for (int q = 0; q < 4; ++q) {
            float4 a = te[q], b4 = pe[q];
            f[4*q+0] = a.x + b4.x; f[4*q+1] = a.y + b4.y;
            f[4*q+2] = a.z + b4.z; f[4*q+3] = a.w + b4.w;
        }
    }
    if (part == 0) {
        float4* fo = (float4*)(featsA + (size_t)node * DIM);
#pragma unroll
        for (int q = 0; q < 4; ++q)
            fo[q] = make_float4(f[4*q], f[4*q+1], f[4*q+2], f[4*q+3]);
        coordsA[node * 3 + 0] = coords[node * 3 + 0];
        coordsA[node * 3 + 1] = coords[node * 3 + 1];
        coordsA[node * 3 + 2] = coords[node * 3 + 2];
    }
    const int ubase = (part & 1) * 33;
    const int wbase = (part < 2) ? 0 : 66;
    float res[36];
    res[33] = 0.f; res[34] = 0.f; res[35] = 0.f;
#pragma unroll
    for (int oo = 0; oo < 33; ++oo) {     // FULL unroll: res[] stays in registers
        const int u = ubase + oo;
        const float* wr = w1tp + (wbase + u) * 16;
        float a0 = (part < 2) ? g_eb1[u] : 0.0f;
        float a1 = 0.f, a2 = 0.f, a3 = 0.f;
#pragma unroll
        for (int c = 0; c < 16; c += 4) {
            a0 = fmaf(f[c + 0], wr[c + 0], a0);
            a1 = fmaf(f[c + 1], wr[c + 1], a1);
            a2 = fmaf(f[c + 2], wr[c + 2], a2);
            a3 = fmaf(f[c + 3], wr[c + 3], a3);
        }
        res[oo] = (a0 + a1) + (a2 + a3);
    }
    float4* op = (float4*)(Pout + (size_t)node * PST + part * 36);
#pragma unroll
    for (int q = 0; q < 9; ++q)
        op[q] = make_float4(res[4*q], res[4*q+1], res[4*q+2], res[4*q+3]);
}

// ---------------- weight transpose/pack ----------------
__global__ __launch_bounds__(256) void pack_kernel(
    const float* __restrict__ ew1, const float* __restrict__ ew2,
    const float* __restrict__ cw1,
    const float* __restrict__ nw1, const float* __restrict__ nw2,
    float* __restrict__ w1tp, float* __restrict__ w1rp, float* __restrict__ w2p,
    float* __restrict__ cw1t, float* __restrict__ nw1t, float* __restrict__ nw2t)
{
    const int stride = gridDim.x * 256;
    const int t0 = blockIdx.x * 256 + threadIdx.x;
    for (int idx = t0; idx < 3 * 132 * 16; idx += stride) {
        int d = idx / (132 * 16); int r = idx - d * 132 * 16; int o = r >> 4; int c = r & 15;
        int u = (o < 66) ? o : (o - 66);
        int cc = (o < 66) ? c : (16 + c);
        w1tp[idx] = ew1[(d * 33 + cc) * 66 + u];
    }
    for (int idx = t0; idx < 3 * 72; idx += stride) {
        int d = idx / 72; int o = idx - d * 72; int hh = o / 36; int uu = o - hh * 36;
        w1rp[idx] = (uu < 33) ? ew1[(d * 33 + 32) * 66 + hh * 33 + uu] : 0.0f;
    }
    for (int idx = t0; idx < 3 * 72 * 16; idx += stride) {
        int d = idx / (72 * 16); int r = idx - d * 72 * 16; int u = r >> 4; int v = r & 15;
        int hh = u / 36; int uu = u - hh * 36;
        w2p[idx] = (uu < 33) ? ew2[(d * 66 + hh * 33 + uu) * 16 + v] : 0.0f;
    }
    for (int idx = t0; idx < 3 * CH * 16; idx += stride) {
        int d = idx / (CH * 16); int r = idx - d * CH * 16; int t = r >> 4; int v = r & 15;
        cw1t[(d * CH + t) * 16 + v] = cw1[(d * 16 + v) * CH + t];
    }
    for (int idx = t0; idx < 3 * NHID * 32; idx += stride) {
        int d = idx / (NHID * 32); int r = idx - d * NHID * 32; int u = r >> 5; int c = r & 31;
        nw1t[(d * NHID + u) * 32 + c] = nw1[(d * 32 + c) * NHID + u];
    }
    for (int idx = t0; idx < 3 * 16 * 32; idx += stride) {
        int d = idx / (16 * 32); int r = idx - d * 16 * 32; int c = r >> 5; int u = r & 31;
        nw2t[(d * 16 + c) * 32 + u] = nw2[(d * 32 + u) * 16 + c];
    }
}

// ---------------- kNN: masked form (1e5 sentinel is load-bearing!) ----------------
__device__ __forceinline__ void merge8(u32* a, const u32* bb) {
    u32 c[8];
#pragma unroll
    for (int t = 0; t < 8; ++t) c[t] = min(a[t], bb[7 - t]);
#define MCAS(x, y) { u32 mn = min(c[x], c[y]); u32 mx = max(c[x], c[y]); c[x] = mn; c[y] = mx; }
    MCAS(0, 4) MCAS(1, 5) MCAS(2, 6) MCAS(3, 7)
    MCAS(0, 2) MCAS(1, 3) MCAS(4, 6) MCAS(5, 7)
    MCAS(0, 1) MCAS(2, 3) MCAS(4, 5) MCAS(6, 7)
#undef MCAS
#pragma unroll
    for (int t = 0; t < 8; ++t) a[t] = c[t];
}

__global__ __launch_bounds__(1024) void knn_kernel(
    const float* __restrict__ coords, const int* __restrict__ lengths,
    int* __restrict__ idxbuf)
{
    __shared__ __align__(16) float4 s_cand[SL];   // 16 KB (padded xyz)
    __shared__ u32 lists[16][64][9];              // 36 KB, pad 9 vs bank conflicts
    const int tid = threadIdx.x;
    const int b = blockIdx.x >> 4;
    const int i0 = (blockIdx.x & 15) << 6;
    const int len = lengths[b];
    const float* cb = coords + (size_t)b * SL * 3;
    for (int idx = tid; idx < SL; idx += 1024) {
        const float* cp = cb + idx * 3;
        s_cand[idx] = make_float4(cp[0], cp[1], cp[2], 0.0f);
    }
    __syncthreads();

    const int wv = tid >> 6;     // candidate slice 0..15
    const int lane = tid & 63;   // query within group
    const int i = i0 + lane;
    const bool mi = i < len;
    const float4 qi = s_cand[i];
    const float xi = qi.x, yi = qi.y, zi = qi.z;

    u32 lst[8];
#pragma unroll
    for (int t = 0; t < 8; ++t) lst[t] = 0xFFFFFFFFu;

    const int jbase = wv << 6;
#pragma unroll 4
    for (int jj = 0; jj < 64; ++jj) {
        const int j = jbase + jj;
        const float4 cj = s_cand[j];   // wave-uniform addr -> LDS broadcast
        const float dx = xi - cj.x, dy = yi - cj.y, dz = zi - cj.z;
        const float dist = dx * dx + dy * dy + dz * dz;
        const int dij = j - i;
        const bool pm = mi && (j < len);
        const bool adjx = (dij == 1) | (dij == -1);
        float v = pm ? (adjx ? 0.0f : dist) : 1e5f;
        v = (dij == 0) ? -1.0f : v;
        u32 bits = __float_as_uint(v);
        bits ^= (u32)((int)bits >> 31) | 0x80000000u;
        const u32 key = (bits & 0xFFFFFC00u) | (u32)j;
        // sorted-insert: lst[p] = min(max(key, lst[p-1]), lst[p]) -- 2 VALU/level
#pragma unroll
        for (int p = 7; p >= 1; --p)
            lst[p] = min(max(key, lst[p - 1]), lst[p]);
        lst[0] = min(key, lst[0]);
    }

#pragma unroll
    for (int t = 0; t < 8; ++t) lists[wv][lane][t] = lst[t];
    __syncthreads();

    if (tid < 512) {
        const int p = tid >> 6, q = tid & 63;
        u32 a[8], bb[8];
#pragma unroll
        for (int t = 0; t < 8; ++t) { a[t] = lists[2 * p][q][t]; bb[t] = lists[2 * p + 1][q][t]; }
        merge8(a, bb);
#pragma unroll
        for (int t = 0; t < 8; ++t) lists[2 * p][q][t] = a[t];
    }
    __syncthreads();
    if (tid < 256) {
        const int p = tid >> 6, q = tid & 63;
        u32 a[8], bb[8];
#pragma unroll
        for (int t = 0; t < 8; ++t) { a[t] = lists[4 * p][q][t]; bb[t] = lists[4 * p + 2][q][t]; }
        merge8(a, bb);
#pragma unroll
        for (int t = 0; t < 8; ++t) lists[4 * p][q][t] = a[t];
    }
    __syncthreads();
    if (tid < 128) {
        const int p = tid >> 6, q = tid & 63;
        u32 a[8], bb[8];
#pragma unroll
        for (int t = 0; t < 8; ++t) { a[t] = lists[8 * p][q][t]; bb[t] = lists[8 * p + 4][q][t]; }
        merge8(a, bb);
#pragma unroll
        for (int t = 0; t < 8; ++t) lists[8 * p][q][t] = a[t];
    }
    __syncthreads();
    if (tid < 64) {
        const int q = tid;
        u32 a[8], bb[8];
#pragma unroll
        for (int t = 0; t < 8; ++t) { a[t] = lists[0][q][t]; bb[t] = lists[8][q][t]; }
        merge8(a, bb);
        const size_t node = (size_t)b * SL + i0 + q;
        int4 r0 = make_int4((int)(a[0] & 1023u), (int)(a[1] & 1023u), (int)(a[2] & 1023u), (int)(a[3] & 1023u));
        int4 r1 = make_int4((int)(a[4] & 1023u), (int)(a[5] & 1023u), (int)(a[6] & 1023u), (int)(a[7] & 1023u));
        ((int4*)idxbuf)[node * 2 + 0] = r0;
        ((int4*)idxbuf)[node * 2 + 1] = r1;
    }
}

// ---------------- EGNN layer: TWO NODES PER THREAD, liveness-disciplined ----------------
// r9 post-mortem: structure right (per-block throughput doubled) but 160 named floats
// spilled (VGPR=64, 70MB scratch). Fix: in-place aliasing (mm->macc, mi->mm, nn->fi),
// fi loaded AFTER m_i reduce, bounds (256,3) for ~168 VGPR headroom. Peak live ~100.
// lane = g(2) | h(1) | k(3): 16 lanes per node-slot, 2 nodes per slot.
__global__ __launch_bounds__(256, 3) void layer_kernel(
    const int d,
    const float* __restrict__ coordsIn, float* __restrict__ coordsOut,
    const float* __restrict__ featsIn, float* __restrict__ featsOut,
    const float* __restrict__ Pbuf,
    const int* __restrict__ idxbuf, const int* __restrict__ lengths,
    const float* __restrict__ w1rp, const float* __restrict__ w2p,
    const float* __restrict__ g_eb2,
    const float* __restrict__ cw1t, const float* __restrict__ g_cb1,
    const float* __restrict__ g_cw2, const float* __restrict__ g_cb2,
    const float* __restrict__ g_lng, const float* __restrict__ g_lnb,
    const float* __restrict__ nw1t, const float* __restrict__ g_nb1,
    const float* __restrict__ nw2t, const float* __restrict__ g_nb2,
    const float* __restrict__ w1tp_all, const float* __restrict__ g_eb1,
    float* __restrict__ PbufOut)
{
    __shared__ float s_w2e[72 * 16];                 // 4608 B
    __shared__ __align__(16) float s_w1r[72];
    __shared__ float s_cw1[CH * 16];                 // 4096 B
    __shared__ float s_cw2v[CH];
    __shared__ float s_nw1[NHID * 36];               // padded rows: bank spread
    __shared__ float s_nw2[16 * 36];
    __shared__ float s_eb2[16], s_cb1[CH];
    __shared__ float s_lng[16], s_lnb[16], s_nb1[32], s_nb2[16];
    __shared__ float s_cb2v;

    const int tid = threadIdx.x;
    for (int t = tid; t < 72 * 16; t += 256) s_w2e[t] = w2p[d * 72 * 16 + t];
    for (int t = tid; t < CH * 16; t += 256) s_cw1[t] = cw1t[d * CH * 16 + t];
    for (int t = tid; t < NHID * 32; t += 256) s_nw1[(t >> 5) * 36 + (t & 31)] = nw1t[d * NHID * 32 + t];
    for (int t = tid; t < 16 * 32; t += 256) s_nw2[(t >> 5) * 36 + (t & 31)] = nw2t[d * 16 * 32 + t];
    if (tid < 72) s_w1r[tid] = w1rp[d * 72 + tid];
    if (tid < CH) { s_cw2v[tid] = g_cw2[d * CH + tid]; s_cb1[tid] = g_cb1[d * CH + tid]; }
    if (tid < 16) {
        s_eb2[tid] = g_eb2[d * 16 + tid];
        s_lng[tid] = g_lng[d * 16 + tid];
        s_lnb[tid] = g_lnb[d * 16 + tid];
        s_nb2[tid] = g_nb2[d * 16 + tid];
    }
    if (tid < 32) s_nb1[tid] = g_nb1[d * 32 + tid];
    if (tid == 0) s_cb2v = g_cb2[d];

    const int lane = tid & 63;
    const int h = (lane >> 3) & 1;               // lane-bit half
    const int k = lane & 7;                      // edge within node
    const int sub = lane & 15;
    const int nA = blockIdx.x * 32 + (tid >> 4); // node A
    const int nB = nA + 16;                      // node B (same batch: 1024%32==0)
    const int b = nA >> 10;
    const int len = lengths[b];
    const int jA = idxbuf[nA * 8 + k];
    const int jB = idxbuf[nB * 8 + k];
    const bool emA = ((nA & 1023) < len) && (jA < len);
    const bool emB = ((nB & 1023) < len) && (jB < len);

    // ---- coords ----
    float ciA[3], relA[3], ciB[3], relB[3];
    {
        const float* cpA = coordsIn + (size_t)nA * 3;
        const float* cqA = coordsIn + ((size_t)b * SL + jA) * 3;
        ciA[0] = cpA[0]; ciA[1] = cpA[1]; ciA[2] = cpA[2];
        relA[0] = ciA[0] - cqA[0]; relA[1] = ciA[1] - cqA[1]; relA[2] = ciA[2] - cqA[2];
        const float* cpB = coordsIn + (size_t)nB * 3;
        const float* cqB = coordsIn + ((size_t)b * SL + jB) * 3;
        ciB[0] = cpB[0]; ciB[1] = cpB[1]; ciB[2] = cpB[2];
        relB[0] = ciB[0] - cqB[0]; relB[1] = ciB[1] - cqB[1]; relB[2] = ciB[2] - cqB[2];
    }
    const float rdA = fmaf(relA[0], relA[0], fmaf(relA[1], relA[1], relA[2] * relA[2]));
    const float rdB = fmaf(relB[0], relB[0], fmaf(relB[1], relB[1], relB[2] * relB[2]));

    const int ub = h * 36;
    const float* PiA = Pbuf + (size_t)nA * PST + ub;
    const float* PjA = Pbuf + ((size_t)b * SL + jA) * PST + 72 + ub;
    const float* PiB = Pbuf + (size_t)nB * PST + ub;
    const float* PjB = Pbuf + ((size_t)b * SL + jB) * PST + 72 + ub;

    __syncthreads();   // weights staged (only barrier in this kernel)

    // ---- edge MLP: layer-1 partials + layer-2 accumulate, weights shared A/B ----
    float maccA[16], maccB[16];
#pragma unroll
    for (int v = 0; v < 16; ++v) {
        const float e0 = h ? 0.0f : s_eb2[v];
        maccA[v] = e0; maccB[v] = e0;
    }
#pragma unroll
    for (int c4 = 0; c4 < 9; ++c4) {
        const float4 paA = *(const float4*)(PiA + 4 * c4);
        const float4 pbA = *(const float4*)(PjA + 4 * c4);
        const float4 paB = *(const float4*)(PiB + 4 * c4);
        const float4 pbB = *(const float4*)(PjB + 4 * c4);
        const int u0 = ub + c4 * 4;
        const float4 w1r4 = *(const float4*)&s_w1r[u0];
        const float huA0 = silu_f(fmaf(rdA, w1r4.x, paA.x + pbA.x));
        const float huA1 = silu_f(fmaf(rdA, w1r4.y, paA.y + pbA.y));
        const float huA2 = silu_f(fmaf(rdA, w1r4.z, paA.z + pbA.z));
        const float huA3 = silu_f(fmaf(rdA, w1r4.w, paA.w + pbA.w));
        const float huB0 = silu_f(fmaf(rdB, w1r4.x, paB.x + pbB.x));
        const float huB1 = silu_f(fmaf(rdB, w1r4.y, paB.y + pbB.y));
        const float huB2 = silu_f(fmaf(rdB, w1r4.z, paB.z + pbB.z));
        const float huB3 = silu_f(fmaf(rdB, w1r4.w, paB.w + pbB.w));
        const float* w2r = &s_w2e[u0 * 16];
#pragma unroll
        for (int v = 0; v < 16; ++v) {
            const float w0 = w2r[v], w1 = w2r[16 + v], w2_ = w2r[32 + v], w3 = w2r[48 + v];
            maccA[v] = fmaf(huA3, w3, fmaf(huA2, w2_, fmaf(huA1, w1, fmaf(huA0, w0, maccA[v]))));
            maccB[v] = fmaf(huB3, w3, fmaf(huB2, w2_, fmaf(huB1, w1, fmaf(huB0, w0, maccB[v]))));
        }
    }

    // ---- combine halves in-wave (partner = lane^8): macc becomes mm IN PLACE ----
#pragma unroll
    for (int v = 0; v < 16; ++v) {
        maccA[v] = silu_f(maccA[v] + __shfl_xor(maccA[v], 8, 64));
        maccB[v] = silu_f(maccB[v] + __shfl_xor(maccB[v], 8, 64));
    }

    // ---- coors MLP, t-range [h*32, h*32+32), weights shared A/B ----
    const int tb = h * 32;
    float waA = 0.f, waB = 0.f;
#pragma unroll 4
    for (int tt = 0; tt < 32; ++tt) {
        const float* cr = &s_cw1[(tb + tt) * 16];
        const float bias = s_cb1[tb + tt];
        float a0A = bias, a1A = 0.f, a0B = bias, a1B = 0.f;
#pragma unroll
        for (int v = 0; v < 16; v += 2) {
            a0A = fmaf(maccA[v], cr[v], a0A);
            a1A = fmaf(maccA[v + 1], cr[v + 1], a1A);
            a0B = fmaf(maccB[v], cr[v], a0B);
            a1B = fmaf(maccB[v + 1], cr[v + 1], a1B);
        }
        const float cw2v = s_cw2v[tb + tt];
        waA = fmaf(silu_f(a0A + a1A), cw2v, waA);
        waB = fmaf(silu_f(a0B + a1B), cw2v, waB);
    }
    const float waoA = __shfl_xor(waA, 8, 64);
    const float waoB = __shfl_xor(waB, 8, 64);
    const float weA = emA ? (waA + waoA + s_cb2v) : 0.f;
    const float weB = emB ? (waB + waoB + s_cb2v) : 0.f;

    // ---- coordinate update: reduce over 8 edges (xor over k bits) ----
    float wr0A = weA * relA[0], wr1A = weA * relA[1], wr2A = weA * relA[2];
    float wr0B = weB * relB[0], wr1B = weB * relB[1], wr2B = weB * relB[2];
#pragma unroll
    for (int s = 1; s < 8; s <<= 1) {
        wr0A += __shfl_xor(wr0A, s, 64);
        wr1A += __shfl_xor(wr1A, s, 64);
        wr2A += __shfl_xor(wr2A, s, 64);
        wr0B += __shfl_xor(wr0B, s, 64);
        wr1B += __shfl_xor(wr1B, s, 64);
        wr2B += __shfl_xor(wr2B, s, 64);
    }
    if ((lane & 15) == 0) {
        coordsOut[(size_t)nA * 3 + 0] = ciA[0] + wr0A;
        coordsOut[(size_t)nA * 3 + 1] = ciA[1] + wr1A;
        coordsOut[(size_t)nA * 3 + 2] = ciA[2] + wr2A;
        coordsOut[(size_t)nB * 3 + 0] = ciB[0] + wr0B;
        coordsOut[(size_t)nB * 3 + 1] = ciB[1] + wr1B;
        coordsOut[(size_t)nB * 3 + 2] = ciB[2] + wr2B;
    }
    // ci/rel dead here.

    // ---- m_i: macc (holding mm) masked + butterfly-reduced IN PLACE ----
#pragma unroll
    for (int v = 0; v < 16; ++v) {
        maccA[v] = emA ? maccA[v] : 0.f;
        maccB[v] = emB ? maccB[v] : 0.f;
        // per-v chain s=1,2,4: bitwise identical to the s-outer/v-inner order
#pragma unroll
        for (int s = 1; s < 8; s <<= 1) {
            maccA[v] += __shfl_xor(maccA[v], s, 64);
            maccB[v] += __shfl_xor(maccB[v], s, 64);
        }
    }
    // macc now holds m_i.

    // ---- feats load (deferred: fi live range starts here) ----
    float fiA[16], fiB[16];
    {
        const float4* ppA = (const float4*)(featsIn + (size_t)nA * DIM);
        float4 a0 = ppA[0], a1 = ppA[1], a2 = ppA[2], a3 = ppA[3];
        fiA[0]=a0.x; fiA[1]=a0.y; fiA[2]=a0.z; fiA[3]=a0.w;
        fiA[4]=a1.x; fiA[5]=a1.y; fiA[6]=a1.z; fiA[7]=a1.w;
        fiA[8]=a2.x; fiA[9]=a2.y; fiA[10]=a2.z; fiA[11]=a2.w;
        fiA[12]=a3.x; fiA[13]=a3.y; fiA[14]=a3.z; fiA[15]=a3.w;
        const float4* ppB = (const float4*)(featsIn + (size_t)nB * DIM);
        float4 b0 = ppB[0], b1 = ppB[1], b2 = ppB[2], b3 = ppB[3];
        fiB[0]=b0.x; fiB[1]=b0.y; fiB[2]=b0.z; fiB[3]=b0.w;
        fiB[4]=b1.x; fiB[5]=b1.y; fiB[6]=b1.z; fiB[7]=b1.w;
        fiB[8]=b2.x; fiB[9]=b2.y; fiB[10]=b2.z; fiB[11]=b2.w;
        fiB[12]=b3.x; fiB[13]=b3.y; fiB[14]=b3.z; fiB[15]=b3.w;
    }
    const float fiSubA = featsIn[(size_t)nA * DIM + sub];   // residual channel
    const float fiSubB = featsIn[(size_t)nB * DIM + sub];

    // ---- LayerNorm: fi becomes nn IN PLACE ----
    {
        float mu = 0.f;
#pragma unroll
        for (int c = 0; c < 16; ++c) mu += fiA[c];
        mu *= 0.0625f;
        float var = 0.f;
#pragma unroll
        for (int c = 0; c < 16; ++c) { const float dd = fiA[c] - mu; var = fmaf(dd, dd, var); }
        var *= 0.0625f;
        const float rs = rsqrtf(var + LN_EPS);
#pragma unroll
        for (int c = 0; c < 16; ++c) fiA[c] = fmaf((fiA[c] - mu) * rs, s_lng[c], s_lnb[c]);
    }
    {
        float mu = 0.f;
#pragma unroll
        for (int c = 0; c < 16; ++c) mu += fiB[c];
        mu *= 0.0625f;
        float var = 0.f;
#pragma unroll
        for (int c = 0; c < 16; ++c) { const float dd = fiB[c] - mu; var = fmaf(dd, dd, var); }
        var *= 0.0625f;
        const float rs = rsqrtf(var + LN_EPS);
#pragma unroll
        for (int c = 0; c < 16; ++c) fiB[c] = fmaf((fiB[c] - mu) * rs, s_lng[c], s_lnb[c]);
    }
    // fi now holds nn; macc holds m_i.

    // ---- node MLP hidden: lane owns units sub*2, sub*2+1; weights shared A/B ----
    float nhA[2], nhB[2];
#pragma unroll
    for (int q = 0; q < 2; ++q) {
        const int u = sub * 2 + q;
        const float* nr = &s_nw1[u * 36];
        const float bias = s_nb1[u];
        float a0A = bias, a1A = 0.f, a0B = bias, a1B = 0.f;
#pragma unroll
        for (int c = 0; c < 16; c += 2) {
            a0A = fmaf(fiA[c], nr[c], a0A);
            a1A = fmaf(fiA[c + 1], nr[c + 1], a1A);
            a0B = fmaf(fiB[c], nr[c], a0B);
            a1B = fmaf(fiB[c + 1], nr[c + 1], a1B);
        }
#pragma unroll
        for (int v = 0; v < 16; v += 2) {
            a0A = fmaf(maccA[v], nr[16 + v], a0A);
            a1A = fmaf(maccA[v + 1], nr[16 + v + 1], a1A);
            a0B = fmaf(maccB[v], nr[16 + v], a0B);
            a1B = fmaf(maccB[v + 1], nr[16 + v + 1], a1B);
        }
        nhA[q] = silu_f(a0A + a1A);
        nhB[q] = silu_f(a0B + a1B);
    }
    // fi(nn) and macc(m_i) dead here.

    // ---- node MLP out: lane computes channel sub; weights shared A/B ----
    const int nbase = lane & ~15;
    const float* w2c = &s_nw2[sub * 36];
    float oA = s_nb2[sub], oB = s_nb2[sub];
#pragma unroll
    for (int u = 0; u < 32; ++u) {
        const float w = w2c[u];
        oA = fmaf(__shfl(nhA[u & 1], nbase + (u >> 1), 64), w, oA);
        oB = fmaf(__shfl(nhB[u & 1], nbase + (u >> 1), 64), w, oB);
    }
    const float foA = fiSubA + oA;
    const float foB = fiSubB + oB;
    featsOut[(size_t)nA * DIM + sub] = foA;
    featsOut[(size_t)nB * DIM + sub] = foB;

    // ---- fused phi for layer d+1: weights (global, L1/L2) shared A/B ----
    if (d < 2) {
        float frA[16], frB[16];
#pragma unroll
        for (int c = 0; c < 16; ++c) {
            frA[c] = __shfl(foA, nbase + c, 64);
            frB[c] = __shfl(foB, nbase + c, 64);
        }
        const float* wbase = w1tp_all + (d + 1) * 132 * 16;
        const float* bbase = g_eb1 + (d + 1) * 66;
        float* PoutA = PbufOut + (size_t)nA * PST;
        float* PoutB = PbufOut + (size_t)nB * PST;
#pragma unroll
        for (int q = 0; q < 9; ++q) {
            const int col = sub + (q << 4);
            const int ch = (col >= 108) ? 3 : (col >= 72) ? 2 : (col >= 36) ? 1 : 0;
            const int uu = col - ch * 36;
            const bool valid = uu < 33;
            const int u = ((ch & 1) ? 33 : 0) + uu;
            const int uc = valid ? u : 0;
            const int widx = valid ? ((ch < 2) ? u : 66 + u) : 0;
            const float bias = (valid && ch < 2) ? bbase[uc] : 0.0f;
            float a0A = bias, a1A = 0.f, a2A = 0.f, a3A = 0.f;
            float a0B = bias, a1B = 0.f, a2B = 0.f, a3B = 0.f;
            const float* wr = wbase + widx * 16;
#pragma unroll
            for (int cc = 0; cc < 16; cc += 4) {
                const float w0 = wr[cc + 0], w1 = wr[cc + 1], w2_ = wr[cc + 2], w3 = wr[cc + 3];
                a0A = fmaf(frA[cc + 0], w0, a0A);
                a1A = fmaf(frA[cc + 1], w1, a1A);
                a2A = fmaf(frA[cc + 2], w2_, a2A);
                a3A = fmaf(frA[cc + 3], w3, a3A);
                a0B = fmaf(frB[cc + 0], w0, a0B);
                a1B = fmaf(frB[cc + 1], w1, a1B);
                a2B = fmaf(frB[cc + 2], w2_, a2B);
                a3B = fmaf(frB[cc + 3], w3, a3B);
            }
            PoutA[col] = valid ? ((a0A + a1A) + (a2A + a3A)) : 0.0f;
            PoutB[col] = valid ? ((a0B + a1B) + (a2B + a3B)) : 0.0f;
        }
    }
}

// ---------------- final projection ----------------
__global__ __launch_bounds__(256) void final_kernel(
    const float* __restrict__ feats, const float* __restrict__ fw,
    const float* __restrict__ fb, float* __restrict__ out)
{
    const int nid = blockIdx.x * 256 + threadIdx.x;
    if (nid >= NB * SL) return;
    float f[DIM];
#pragma unroll
    for (int c = 0; c < DIM; ++c) f[c] = feats[nid * DIM + c];
#pragma unroll
    for (int o = 0; o < 3; ++o) {
        float acc = fb[o];
#pragma unroll
        for (int c = 0; c < DIM; ++c) acc = fmaf(f[c], fw[c * 3 + o], acc);
        out[nid * 3 + o] = acc;
    }
}

extern "C" void kernel_launch(void* const* d_in, const int* in_sizes, int n_in,
                              void* d_out, int out_size, void* d_ws, size_t ws_size,
                              hipStream_t stream) {
    const float* coords    = (const float*)d_in[0];
    const int*   residues  = (const int*)d_in[1];
    const int*   lengths   = (const int*)d_in[2];
    const float* token_emb = (const float*)d_in[3];
    const float* pos_emb   = (const float*)d_in[4];
    const float* ew1 = (const float*)d_in[5];
    const float* eb1 = (const float*)d_in[6];
    const float* ew2 = (const float*)d_in[7];
    const float* eb2 = (const float*)d_in[8];
    const float* cw1 = (const float*)d_in[9];
    const float* cb1 = (const float*)d_in[10];
    const float* cw2 = (const float*)d_in[11];
    const float* cb2 = (const float*)d_in[12];
    const float* lng = (const float*)d_in[13];
    const float* lnb = (const float*)d_in[14];
    const float* nw1 = (const float*)d_in[15];
    const float* nb1 = (const float*)d_in[16];
    const float* nw2 = (const float*)d_in[17];
    const float* nb2 = (const float*)d_in[18];
    const float* fw  = (const float*)d_in[19];
    const float* fb  = (const float*)d_in[20];

    float* ws = (float*)d_ws;
    float* coordsA = ws;
    float* coordsB = coordsA + NB * SL * 3;
    float* featsA  = coordsB + NB * SL * 3;
    float* featsB  = featsA + NB * SL * DIM;
    int*   idxbuf  = (int*)(featsB + NB * SL * DIM);
    float* w1tp = (float*)(idxbuf + NB * SL * KNN);     // 3*132*16
    float* w1rp = w1tp + 3 * 132 * 16;                  // 3*72
    float* w2p  = w1rp + 3 * 72;                        // 3*72*16
    float* cw1t = w2p + 3 * 72 * 16;                    // 3*64*16
    float* nw1t = cw1t + 3 * CH * 16;                   // 3*32*32
    float* nw2t = nw1t + 3 * NHID * 32;                 // 3*16*32
    float* PbufA = nw2t + 3 * 16 * 32;                  // 16384*144
    float* PbufB = PbufA + (size_t)NB * SL * PST;       // 16384*144

    pack_kernel<<<32, 256, 0, stream>>>(ew1, ew2, cw1, nw1, nw2, w1tp, w1rp, w2p, cw1t, nw1t, nw2t);
    init_kernel<<<NB * SL * 4 / 256, 256, 0, stream>>>(coords, residues, token_emb, pos_emb,
                                                        w1tp, eb1, coordsA, featsA, PbufA);

    float* cIn = coordsA; float* cOut = coordsB;
    float* fIn = featsA;  float* fOut = featsB;
    float* pIn = PbufA;   float* pOut = PbufB;
    for (int d = 0; d < 3; ++d) {
        knn_kernel<<<NB * SL / 64, 1024, 0, stream>>>(cIn, lengths, idxbuf);
        layer_kernel<<<NB * SL * KNN / 256, 256, 0, stream>>>(d, cIn, cOut, fIn, fOut, pIn, idxbuf, lengths,
            w1rp, w2p, eb2, cw1t, cb1, cw2, cb2, lng, lnb, nw1t, nb1, nw2t, nb2,
            w1tp, eb1, pOut);
        float* t;
        t = cIn; cIn = cOut; cOut = t;
        t = fIn; fIn = fOut; fOut = t;
        t = pIn; pIn = pOut; pOut = t;
    }

    final_kernel<<<NB * SL / 256, 256, 0, stream>>>(fIn, fw, fb, (float*)d_out);
}